// Round 1
// baseline (355.376 us; speedup 1.0000x reference)
//
#include <hip/hip_runtime.h>
#include <hip/hip_bf16.h>

#define N_NODES 50000
#define N_EDGES 800000
#define KPTS 15
#define IN_DIM 32
#define OUT_DIM 64
#define KP_EXTENT 0.6f
#define KI (KPTS * IN_DIM)   // 480

// ---------------------------------------------------------------------------
// Phase 1: per-edge scatter.  32 threads (= IN_DIM) per edge; lane = channel.
// wf layout: [node][k][in]  (row stride KI floats)
// ---------------------------------------------------------------------------
__global__ __launch_bounds__(256) void edge_scatter(
    const float* __restrict__ pos,
    const float* __restrict__ feat,
    const float* __restrict__ kp,
    const int*   __restrict__ esrc,
    const int*   __restrict__ edst,
    float*       __restrict__ wf)
{
    const int lane = threadIdx.x & 31;
    const int eib  = threadIdx.x >> 5;            // edge-in-block 0..7
    const long long e = (long long)blockIdx.x * 8 + eib;
    if (e >= N_EDGES) return;

    const int s = esrc[e];
    const int d = edst[e];

    const float yx = pos[s * 3 + 0] - pos[d * 3 + 0];
    const float yy = pos[s * 3 + 1] - pos[d * 3 + 1];
    const float yz = pos[s * 3 + 2] - pos[d * 3 + 2];

    const float f = feat[(long long)s * IN_DIM + lane];   // coalesced 128B/edge

    float* base = wf + (long long)d * KI + lane;

    #pragma unroll
    for (int k = 0; k < KPTS; ++k) {
        const float dx = yx - kp[k * 3 + 0];
        const float dy = yy - kp[k * 3 + 1];
        const float dz = yz - kp[k * 3 + 2];
        const float dist = sqrtf(dx * dx + dy * dy + dz * dz);
        const float m = 1.0f - dist * (1.0f / KP_EXTENT);
        if (m > 0.0f) {                            // uniform across the 32 lanes
            atomicAdd(base + k * IN_DIM, m * f);
        }
    }
}

// ---------------------------------------------------------------------------
// Phase 2: out[N,64] = wf[N,480] @ W[480,64].
// 16 nodes per block staged in LDS; thread = (o = tid&63, node stripe tid>>6).
// ---------------------------------------------------------------------------
__global__ __launch_bounds__(256) void node_matmul(
    const float* __restrict__ wf,
    const float* __restrict__ W,     // [480][64] contiguous (= weights [15][32][64])
    float*       __restrict__ out)
{
    __shared__ float srow[16][KI];   // 30720 B

    const int nb = blockIdx.x * 16;

    for (int idx = threadIdx.x; idx < 16 * KI; idx += 256) {
        const int nl = idx / KI;
        const int ki = idx - nl * KI;
        const int n  = nb + nl;
        srow[nl][ki] = (n < N_NODES) ? wf[(long long)n * KI + ki] : 0.0f;
    }
    __syncthreads();

    const int o   = threadIdx.x & 63;
    const int nl0 = threadIdx.x >> 6;   // 0..3

    float acc0 = 0.f, acc1 = 0.f, acc2 = 0.f, acc3 = 0.f;

    for (int ki = 0; ki < KI; ++ki) {
        const float w = W[ki * OUT_DIM + o];     // coalesced 256B/wave, L1/L2-hot
        acc0 += srow[nl0 + 0][ki] * w;           // LDS broadcast (same addr/wave)
        acc1 += srow[nl0 + 4][ki] * w;
        acc2 += srow[nl0 + 8][ki] * w;
        acc3 += srow[nl0 + 12][ki] * w;
    }

    const int n0 = nb + nl0;
    if (n0 + 0  < N_NODES) out[(long long)(n0 + 0)  * OUT_DIM + o] = acc0;
    if (n0 + 4  < N_NODES) out[(long long)(n0 + 4)  * OUT_DIM + o] = acc1;
    if (n0 + 8  < N_NODES) out[(long long)(n0 + 8)  * OUT_DIM + o] = acc2;
    if (n0 + 12 < N_NODES) out[(long long)(n0 + 12) * OUT_DIM + o] = acc3;
}

// ---------------------------------------------------------------------------
extern "C" void kernel_launch(void* const* d_in, const int* in_sizes, int n_in,
                              void* d_out, int out_size, void* d_ws, size_t ws_size,
                              hipStream_t stream)
{
    const float* pos  = (const float*)d_in[0];   // [50000,3]
    const float* feat = (const float*)d_in[1];   // [50000,32]
    const float* kp   = (const float*)d_in[2];   // [15,3]
    const float* W    = (const float*)d_in[3];   // [15,32,64]
    const int* esrc   = (const int*)d_in[4];     // [800000]
    const int* edst   = (const int*)d_in[5];     // [800000]
    float* out        = (float*)d_out;           // [50000,64]

    float* wf = (float*)d_ws;                    // [50000,480] = 96 MB
    const size_t wf_bytes = (size_t)N_NODES * KI * sizeof(float);

    hipMemsetAsync(wf, 0, wf_bytes, stream);

    const int eblocks = (N_EDGES + 7) / 8;       // 8 edges/block (32 thr/edge)
    edge_scatter<<<eblocks, 256, 0, stream>>>(pos, feat, kp, esrc, edst, wf);

    const int nblocks = (N_NODES + 15) / 16;
    node_matmul<<<nblocks, 256, 0, stream>>>(wf, W, out);
}

// Round 2
// 178.187 us; speedup vs baseline: 1.9944x; 1.9944x over previous
//
#include <hip/hip_runtime.h>
#include <hip/hip_bf16.h>

#define N_NODES 50000
#define N_EDGES 800000
#define KPTS 15
#define IN_DIM 32
#define OUT_DIM 64
#define KP_EXTENT 0.6f

#define CAP 131072          // per-k list capacity (expected ~13k/k, 10x margin)
#define CNT_STRIDE 64       // ints: 256B between counters -> distinct L2 channels
#define K1_BLOCKS (N_EDGES / 256)   // 800000/256 = 3125 exactly
#define BPK 64              // blocks per kernel-point in K2

// ws layout: [0, 4096) padded counters; [4096, ...) 15 lists of CAP uint2
#define LIST_OFF 4096

// ---------------------------------------------------------------------------
// K1: geometry (1 lane = 1 edge) + ballot compaction into per-k pair lists.
// ---------------------------------------------------------------------------
__global__ __launch_bounds__(256) void geom_compact(
    const float* __restrict__ pos,
    const float* __restrict__ kp,
    const int*   __restrict__ esrc,
    const int*   __restrict__ edst,
    int*         __restrict__ cnt,     // padded counters
    uint2*       __restrict__ lists)   // 15 * CAP entries
{
    __shared__ int s_wavecnt[KPTS][4];
    __shared__ int s_woff[KPTS][4];
    __shared__ int s_base[KPTS];

    const int tid  = threadIdx.x;
    const int wv   = tid >> 6;
    const int lane = tid & 63;

    const int e = blockIdx.x * 256 + tid;      // grid covers E exactly
    const int s = esrc[e];
    const int d = edst[e];

    const float yx = pos[s * 3 + 0] - pos[d * 3 + 0];
    const float yy = pos[s * 3 + 1] - pos[d * 3 + 1];
    const float yz = pos[s * 3 + 2] - pos[d * 3 + 2];

    float m[KPTS];
    unsigned act = 0;
    #pragma unroll
    for (int k = 0; k < KPTS; ++k) {
        const float dx = yx - kp[k * 3 + 0];
        const float dy = yy - kp[k * 3 + 1];
        const float dz = yz - kp[k * 3 + 2];
        const float dist = sqrtf(dx * dx + dy * dy + dz * dz);
        const float mk = 1.0f - dist * (1.0f / KP_EXTENT);
        m[k] = mk;
        if (mk > 0.0f) act |= (1u << k);
    }

    // per-wave popcounts
    #pragma unroll
    for (int k = 0; k < KPTS; ++k) {
        const unsigned long long mask = __ballot((act >> k) & 1u);
        if (lane == 0) s_wavecnt[k][wv] = __popcll(mask);
    }
    __syncthreads();

    if (tid < KPTS) {
        int o0 = 0;
        int total = 0;
        #pragma unroll
        for (int w = 0; w < 4; ++w) {
            s_woff[tid][w] = o0;
            o0 += s_wavecnt[tid][w];
        }
        total = o0;
        s_base[tid] = (total > 0) ? atomicAdd(&cnt[tid * CNT_STRIDE], total) : 0;
    }
    __syncthreads();

    const unsigned long long lt = (lane == 63) ? 0x7fffffffffffffffull
                                               : ((1ull << lane) - 1ull);
    const unsigned sd = ((unsigned)s << 16) | (unsigned)d;
    #pragma unroll
    for (int k = 0; k < KPTS; ++k) {
        const bool a = (act >> k) & 1u;
        const unsigned long long mask = __ballot(a);
        if (a) {
            const int rank = __popcll(mask & lt);
            const int idx  = s_base[k] + s_woff[k][wv] + rank;
            if (idx < CAP)
                lists[(size_t)k * CAP + idx] = make_uint2(sd, __float_as_uint(m[k]));
        }
    }
}

// ---------------------------------------------------------------------------
// K2: one wave per active pair; lane = output channel. W[k] column held in
// 32 VGPRs per lane; feat row arrives as uniform (scalar) loads.
// ---------------------------------------------------------------------------
__global__ __launch_bounds__(256) void pair_matmul(
    const float* __restrict__ feat,
    const float* __restrict__ W,       // [15][32][64]
    const int*   __restrict__ cnt,
    const uint2* __restrict__ lists,
    float*       __restrict__ out)
{
    const int k    = blockIdx.x % KPTS;
    const int bk   = blockIdx.x / KPTS;          // 0..BPK-1
    const int wv   = threadIdx.x >> 6;
    const int lane = threadIdx.x & 63;

    // preload W[k][i][lane], i = 0..31  -> 32 VGPRs
    float w[IN_DIM];
    #pragma unroll
    for (int i = 0; i < IN_DIM; ++i)
        w[i] = W[k * (IN_DIM * OUT_DIM) + i * OUT_DIM + lane];

    const int n = cnt[k * CNT_STRIDE];
    const uint2* list = lists + (size_t)k * CAP;

    const int widx   = bk * 4 + wv;              // 0..255
    const int stride = BPK * 4;

    for (int p = widx; p < n; p += stride) {
        const uint2 ent = list[p];               // same addr across wave
        const unsigned sd = (unsigned)__builtin_amdgcn_readfirstlane((int)ent.x);
        const float m = __uint_as_float(ent.y);
        const int s = (int)(sd >> 16);
        const int d = (int)(sd & 0xffffu);

        const float* __restrict__ f = feat + (s << 5);   // uniform -> s_load
        float acc = 0.0f;
        #pragma unroll
        for (int i = 0; i < IN_DIM; ++i)
            acc = fmaf(f[i], w[i], acc);

        atomicAdd(out + (size_t)d * OUT_DIM + lane, m * acc);
    }
}

// ---------------------------------------------------------------------------
extern "C" void kernel_launch(void* const* d_in, const int* in_sizes, int n_in,
                              void* d_out, int out_size, void* d_ws, size_t ws_size,
                              hipStream_t stream)
{
    const float* pos  = (const float*)d_in[0];   // [50000,3]
    const float* feat = (const float*)d_in[1];   // [50000,32]
    const float* kp   = (const float*)d_in[2];   // [15,3]
    const float* W    = (const float*)d_in[3];   // [15,32,64]
    const int* esrc   = (const int*)d_in[4];     // [800000]
    const int* edst   = (const int*)d_in[5];     // [800000]
    float* out        = (float*)d_out;           // [50000,64]

    int*   cnt   = (int*)d_ws;
    uint2* lists = (uint2*)((char*)d_ws + LIST_OFF);

    hipMemsetAsync(cnt, 0, LIST_OFF, stream);
    hipMemsetAsync(out, 0, (size_t)N_NODES * OUT_DIM * sizeof(float), stream);

    geom_compact<<<K1_BLOCKS, 256, 0, stream>>>(pos, kp, esrc, edst, cnt, lists);
    pair_matmul<<<BPK * KPTS, 256, 0, stream>>>(feat, W, cnt, lists, out);
}